// Round 21
// baseline (224.093 us; speedup 1.0000x reference)
//
#include <hip/hip_runtime.h>
#include <hip/hip_bf16.h>
#include <stdint.h>

#define NPROT 19000
#define NDRUG 4000
#define NCELL 16
#define BATCH 4096
#define NEDGE 40000
#define L0 2048
#define L1DIM 1024
#define INDIM 38032
#define HALFDIM 19016
#define DCAP 96      // max deduped proteins per drug (avg 10, tail << 96)
#define BMWORDS ((NDRUG * NPROT + 31) / 32)   // dedup bitmap words
#define PSPLIT 9504  // protein split point (half 0: [0,9504), half 1: [9504,19000))
#define WSLOT 9504   // dummy slot (local index)
#define WSTN2 9512   // uint2 slots: 9504 + 8 pad

typedef float f32x4 __attribute__((ext_vector_type(4)));
typedef short s16x8 __attribute__((ext_vector_type(8)));

__global__ void zero_all_kernel(int* __restrict__ p, int n) {
    int i = blockIdx.x * 256 + threadIdx.x;
    if (i < n) p[i] = 0;
}

// dedup via bitmap; count per (drug, protein-half); append to per-drug list
__global__ void scatter_dedup_kernel(const int* __restrict__ drug, const int* __restrict__ prot,
                                     unsigned* __restrict__ bitmap, int* __restrict__ cnt2,
                                     int* __restrict__ cntTot, unsigned short* __restrict__ dlist) {
    int e = blockIdx.x * 256 + threadIdx.x;
    if (e < NEDGE) {
        int d = drug[e], p = prot[e];
        unsigned idx = (unsigned)d * NPROT + p;
        unsigned bit = 1u << (idx & 31u);
        unsigned old = atomicOr(&bitmap[idx >> 5], bit);
        if (!(old & bit)) {
            int ph = p >= PSPLIT;
            atomicAdd(&cnt2[d * 2 + ph], 1);
            int pos = atomicAdd(&cntTot[d], 1);
            if (pos < DCAP) dlist[d * DCAP + pos] = (unsigned short)p;
        }
    }
}

// per-slot prefix over 8 owned drugs for BOTH protein halves; 16 streams total
__global__ __launch_bounds__(512) void stream_meta_kernel(const int* __restrict__ cnt2,
                                                          int* __restrict__ wlen,
                                                          int* __restrict__ wbase,
                                                          int* __restrict__ pref,
                                                          int* __restrict__ tcnt) {
    __shared__ int wl[16];
    int t = threadIdx.x;
    if (t < 16) wl[t] = 0;
    __syncthreads();
    int c0 = 0, c1 = 0;
#pragma unroll
    for (int k = 0; k < 8; ++k) {
        int d = t + (k << 9);
        pref[((t << 3) + k) * 2 + 0] = c0;
        pref[((t << 3) + k) * 2 + 1] = c1;
        if (d < NDRUG) {
            int n0 = cnt2[d * 2], n1 = cnt2[d * 2 + 1];
            c0 += n0 ? n0 : 1;
            c1 += n1 ? n1 : 1;
        }
    }
    tcnt[t * 2] = c0;
    tcnt[t * 2 + 1] = c1;
    atomicMax(&wl[(t >> 6) * 2], c0);
    atomicMax(&wl[(t >> 6) * 2 + 1], c1);
    __syncthreads();
    if (t == 0) {
        int run = 0;
        for (int s = 0; s < 16; ++s) {
            wlen[s] = wl[s];
            wbase[s] = run;
            run += wl[s] * 64;
        }
    }
}

// drug-parallel fill of the 16 wave-interleaved u16 streams.
// entry = local_p | (last<<15); slot t's i-th entry of stream s at wbase[s]+(t&63)+i*64
__global__ __launch_bounds__(256) void fill_stream_kernel(const int* __restrict__ cnt2,
                                                          const unsigned short* __restrict__ dlist,
                                                          const int* __restrict__ wbase,
                                                          const int* __restrict__ wlen,
                                                          const int* __restrict__ pref,
                                                          const int* __restrict__ tcnt,
                                                          unsigned short* __restrict__ estream) {
    int g = blockIdx.x * 256 + threadIdx.x;
    if (g < NDRUG) {
        int d = g;
        int t = d & 511, k = d >> 9;
        int wv = t >> 6, lane = t & 63;
        int n0 = cnt2[d * 2], n1 = cnt2[d * 2 + 1];
        int base0 = wbase[wv * 2 + 0] + lane;
        int base1 = wbase[wv * 2 + 1] + lane;
        int i0 = pref[((t << 3) + k) * 2 + 0];
        int i1 = pref[((t << 3) + k) * 2 + 1];
        int n = min(n0 + n1, DCAP);
        int j0 = 0, j1 = 0;
        for (int i = 0; i < n; ++i) {
            int p = dlist[d * DCAP + i];
            if (p < PSPLIT) {
                unsigned short e = (unsigned short)(p | ((j0 == n0 - 1) ? 0x8000 : 0));
                estream[base0 + (i0 + j0) * 64] = e;
                ++j0;
            } else {
                unsigned short e = (unsigned short)((p - PSPLIT) | ((j1 == n1 - 1) ? 0x8000 : 0));
                estream[base1 + (i1 + j1) * 64] = e;
                ++j1;
            }
        }
        if (n0 == 0) estream[base0 + i0 * 64] = (unsigned short)(WSLOT | 0x8000);
        if (n1 == 0) estream[base1 + i1 * 64] = (unsigned short)(WSLOT | 0x8000);
    } else if (g < NDRUG + 1024) {
        int idx = g - NDRUG;
        int t = idx >> 1, ph = idx & 1;
        int wv = t >> 6;
        int base = wbase[wv * 2 + ph] + (t & 63);
        int wl = wlen[wv * 2 + ph];
        for (int j = tcnt[t * 2 + ph]; j < wl; ++j)
            estream[base + j * 64] = (unsigned short)WSLOT;
    }
}

// RNE f32->bf16 pair pack: low16 = a, high16 = b
__device__ inline unsigned bfpair(float a, float b) {
    unsigned ua = __float_as_uint(a), ub = __float_as_uint(b);
    ua += 0x7fffu + ((ua >> 16) & 1u);
    ub += 0x7fffu + ((ub >> 16) & 1u);
    return (ua >> 16) | (ub & 0xffff0000u);
}
__device__ inline float bflo(unsigned w) { return __uint_as_float(w << 16); }
__device__ inline float bfhi(unsigned w) { return __uint_as_float(w & 0xffff0000u); }

// merged independent prep work (one launch instead of three):
//  blocks [0,2048):    cvtw1  (W1 f32 -> W1b bf16, one float4/thread)
//  blocks [2048,2176): base   (BASE[c][ch] = b0 + W0 cell cols)
//  blocks [2176,2208): init_out (out[i] = b2)
__global__ __launch_bounds__(256) void misc_kernel(const float* __restrict__ W0,
                                                   const float* __restrict__ b0,
                                                   float* __restrict__ BASE,
                                                   const float* __restrict__ W1,
                                                   __hip_bfloat16* __restrict__ W1b,
                                                   const float* __restrict__ b2,
                                                   float* __restrict__ out) {
    int b = blockIdx.x;
    int t = threadIdx.x;
    if (b < 2048) {
        int i = b * 256 + t;                 // < 524288 = L1DIM*L0/4
        float4 v = ((const float4*)W1)[i];
        uint2 q;
        q.x = bfpair(v.x, v.y);
        q.y = bfpair(v.z, v.w);
        ((uint2*)W1b)[i] = q;
    } else if (b < 2176) {
        int i = (b - 2048) * 256 + t;        // < 32768 = NCELL*L0
        int c = i >> 11, ch = i & 2047;
        const float* wr = W0 + (size_t)ch * INDIM;
        BASE[(size_t)c * L0 + ch] = b0[ch] + wr[NPROT + c] + wr[HALFDIM + NPROT + c];
    } else {
        int i = (b - 2176) * 256 + t;        // < 8192 = 2*BATCH
        out[i] = b2[0];
    }
}

// Split-protein drug sum: block = (protein-half ph, W0-half hb, ch-quad).
// Stage 9504 prot x 4ch packed bf16 = 76KB -> 2 blocks/CU. Walk: per 8-entry
// batch, phase 1 issues all 8 ds_read_b64 (no side effects between reads),
// phase 2 accumulates + flag-stores -> LDS latency paid once per batch, not 8x.
// Emits bf16 partials coalesced: SAT[row][d], row = ph*1024 + hb*512 + quad.
__global__ __launch_bounds__(512) void drug_sum_kernel(const float* __restrict__ W0,
                                                       const unsigned short* __restrict__ estream,
                                                       const int* __restrict__ wbase,
                                                       const int* __restrict__ wlen,
                                                       uint2* __restrict__ SAT) {
    __shared__ uint2 wst[WSTN2];  // 76096 B
    int t = threadIdx.x;
    int bid = blockIdx.x;         // 2048 = ph*1024 + hb*512 + quad
    int ph = bid >> 10;
    int k3 = bid & 1023;
    int hb = k3 >> 9;
    int quad = k3 & 511;
    int ch0 = quad * 4;
    size_t colbase = (size_t)hb * HALFDIM + (size_t)ph * PSPLIT;
    int pc = ph ? (NPROT - PSPLIT) : PSPLIT;   // 9496 or 9504

    // prefetch first estream batch (independent of wst)
    int wv = t >> 6;
    int sid = wv * 2 + ph;
    int base = wbase[sid] + (t & 63);
    int wl = wlen[sid];
    int nfull = wl >> 3, rem = wl & 7;
    unsigned e[8];
    if (nfull > 0) {
#pragma unroll
        for (int k = 0; k < 8; ++k) e[k] = estream[base + k * 64];
        base += 512;
    }

    const float* sA = W0 + (size_t)(ch0 + 0) * INDIM + colbase;
    const float* sB = W0 + (size_t)(ch0 + 1) * INDIM + colbase;
    const float* sC = W0 + (size_t)(ch0 + 2) * INDIM + colbase;
    const float* sD = W0 + (size_t)(ch0 + 3) * INDIM + colbase;
#pragma unroll
    for (int k = 0; k < 4; ++k) {
        int i = t * 4 + k * 2048;   // max 8188 < 9496 : uniform
        float4 a = *(const float4*)(sA + i);
        float4 b = *(const float4*)(sB + i);
        float4 c = *(const float4*)(sC + i);
        float4 d = *(const float4*)(sD + i);
        uint4 q0, q1;
        q0.x = bfpair(a.x, b.x); q0.y = bfpair(c.x, d.x);
        q0.z = bfpair(a.y, b.y); q0.w = bfpair(c.y, d.y);
        q1.x = bfpair(a.z, b.z); q1.y = bfpair(c.z, d.z);
        q1.z = bfpair(a.w, b.w); q1.w = bfpair(c.w, d.w);
        *(uint4*)&wst[i] = q0;
        *(uint4*)&wst[i + 2] = q1;
    }
    {
        int i = t * 4 + 8192;
        if (i < pc) {
            float4 a = *(const float4*)(sA + i);
            float4 b = *(const float4*)(sB + i);
            float4 c = *(const float4*)(sC + i);
            float4 d = *(const float4*)(sD + i);
            uint4 q0, q1;
            q0.x = bfpair(a.x, b.x); q0.y = bfpair(c.x, d.x);
            q0.z = bfpair(a.y, b.y); q0.w = bfpair(c.y, d.y);
            q1.x = bfpair(a.z, b.z); q1.y = bfpair(c.z, d.z);
            q1.z = bfpair(a.w, b.w); q1.w = bfpair(c.w, d.w);
            *(uint4*)&wst[i] = q0;
            *(uint4*)&wst[i + 2] = q1;
        }
    }
    if (t < 8) { wst[WSLOT + t].x = 0u; wst[WSLOT + t].y = 0u; }
    __syncthreads();

    float x0 = 0.f, x1 = 0.f, x2 = 0.f, x3 = 0.f;
    int kk = 0;
    uint2* dstT = SAT + (size_t)bid * 4096;

    // phase-split batch: 8 independent LDS reads, then accumulate+flag
    auto procBatch = [&](const unsigned* ev) {
        uint2 w[8];
#pragma unroll
        for (int k = 0; k < 8; ++k) w[k] = wst[ev[k] & 0x7fffu];
#pragma unroll
        for (int k = 0; k < 8; ++k) {
            x0 += bflo(w[k].x);
            x1 += bfhi(w[k].x);
            x2 += bflo(w[k].y);
            x3 += bfhi(w[k].y);
            if (ev[k] & 0x8000u) {
                uint2 v;
                v.x = bfpair(x0, x1);
                v.y = bfpair(x2, x3);
                dstT[t + (kk << 9)] = v;    // slot == drug id (t + kk*512)
                ++kk; x0 = 0.f; x1 = 0.f; x2 = 0.f; x3 = 0.f;
            }
        }
    };

    if (nfull > 0) {
        for (int it = 1; it < nfull; ++it) {
            unsigned f[8];
#pragma unroll
            for (int k = 0; k < 8; ++k) f[k] = estream[base + k * 64];
            base += 512;
            procBatch(e);
#pragma unroll
            for (int k = 0; k < 8; ++k) e[k] = f[k];
        }
        procBatch(e);
    }
    for (int k = 0; k < rem; ++k) {
        unsigned ev = estream[base + k * 64];
        uint2 w = wst[ev & 0x7fffu];
        x0 += bflo(w.x);
        x1 += bfhi(w.x);
        x2 += bflo(w.y);
        x3 += bfhi(w.y);
        if (ev & 0x8000u) {
            uint2 v;
            v.x = bfpair(x0, x1);
            v.y = bfpair(x2, x3);
            dstT[t + (kk << 9)] = v;
            ++kk; x0 = 0.f; x1 = 0.f; x2 = 0.f; x3 = 0.f;
        }
    }
}

// combine + transpose + pack: SAb/SBb[d][2048] bf16 = (ph0 + ph1) bf16 partials
// grid: 2 hb x 16 quad-tiles x 125 drug-tiles = 4000 blocks of 256
__global__ __launch_bounds__(256) void combine_kernel(const uint2* __restrict__ SAT,
                                                      __hip_bfloat16* __restrict__ SAb,
                                                      __hip_bfloat16* __restrict__ SBb) {
    __shared__ float tile[4][32][33];
    int b = blockIdx.x;
    int hb = b / 2000;
    int rem = b % 2000;
    int q0 = (rem / 125) * 32;
    int d0 = (rem % 125) * 32;
    const uint2* inA = SAT + (size_t)(hb * 512) * 4096;          // ph=0
    const uint2* inB = SAT + (size_t)(1024 + hb * 512) * 4096;   // ph=1
    int tx = threadIdx.x & 31, ty = threadIdx.x >> 5;   // 32 x 8
#pragma unroll
    for (int r = 0; r < 32; r += 8) {
        int q = q0 + r + ty;
        uint2 a = inA[(size_t)q * 4096 + d0 + tx];
        uint2 c = inB[(size_t)q * 4096 + d0 + tx];
        tile[0][r + ty][tx] = bflo(a.x) + bflo(c.x);
        tile[1][r + ty][tx] = bfhi(a.x) + bfhi(c.x);
        tile[2][r + ty][tx] = bflo(a.y) + bflo(c.y);
        tile[3][r + ty][tx] = bfhi(a.y) + bfhi(c.y);
    }
    __syncthreads();
    __hip_bfloat16* out = hb ? SBb : SAb;
#pragma unroll
    for (int r = 0; r < 32; r += 8) {
        int d = d0 + r + ty;
        float x = tile[0][tx][r + ty];
        float y = tile[1][tx][r + ty];
        float z = tile[2][tx][r + ty];
        float w = tile[3][tx][r + ty];
        uint2 v;
        v.x = bfpair(x, y);
        v.y = bfpair(z, w);
        *(uint2*)(out + (size_t)d * L0 + (q0 + tx) * 4) = v;
    }
}

// h1[b]      = relu(BASE[c] + SA[d1] + SB[d2])  (x1)
// h1[4096+b] = relu(BASE[c] + SA[d2] + SB[d1])  (x2)
__global__ __launch_bounds__(256) void build_h_kernel(const int* __restrict__ dp,
                                                      const int* __restrict__ cl,
                                                      const __hip_bfloat16* __restrict__ SAb,
                                                      const __hip_bfloat16* __restrict__ SBb,
                                                      const float* __restrict__ BASE,
                                                      __hip_bfloat16* __restrict__ h1) {
    int b = blockIdx.x;
    int d1 = dp[2 * b], d2 = dp[2 * b + 1], c = cl[b];
    int ch = threadIdx.x * 8;
    const float* bs = BASE + (size_t)c * L0 + ch;
    uint4 ua1 = *(const uint4*)(SAb + (size_t)d1 * L0 + ch);
    uint4 ua2 = *(const uint4*)(SAb + (size_t)d2 * L0 + ch);
    uint4 us1 = *(const uint4*)(SBb + (size_t)d1 * L0 + ch);
    uint4 us2 = *(const uint4*)(SBb + (size_t)d2 * L0 + ch);
    float4 vb0 = *(const float4*)(bs);
    float4 vb1 = *(const float4*)(bs + 4);
    float bsv[8] = {vb0.x, vb0.y, vb0.z, vb0.w, vb1.x, vb1.y, vb1.z, vb1.w};
    unsigned a1w[4] = {ua1.x, ua1.y, ua1.z, ua1.w};
    unsigned a2w[4] = {ua2.x, ua2.y, ua2.z, ua2.w};
    unsigned s1w[4] = {us1.x, us1.y, us1.z, us1.w};
    unsigned s2w[4] = {us2.x, us2.y, us2.z, us2.w};
    float z1[8], z2[8];
#pragma unroll
    for (int k = 0; k < 4; ++k) {
        z1[2 * k]     = fmaxf(bsv[2 * k]     + bflo(a1w[k]) + bflo(s2w[k]), 0.f);
        z1[2 * k + 1] = fmaxf(bsv[2 * k + 1] + bfhi(a1w[k]) + bfhi(s2w[k]), 0.f);
        z2[2 * k]     = fmaxf(bsv[2 * k]     + bflo(a2w[k]) + bflo(s1w[k]), 0.f);
        z2[2 * k + 1] = fmaxf(bsv[2 * k + 1] + bfhi(a2w[k]) + bfhi(s1w[k]), 0.f);
    }
    uint4 o1, o2;
    o1.x = bfpair(z1[0], z1[1]); o1.y = bfpair(z1[2], z1[3]);
    o1.z = bfpair(z1[4], z1[5]); o1.w = bfpair(z1[6], z1[7]);
    o2.x = bfpair(z2[0], z2[1]); o2.y = bfpair(z2[2], z2[3]);
    o2.z = bfpair(z2[4], z2[5]); o2.w = bfpair(z2[6], z2[7]);
    *(uint4*)((__hip_bfloat16*)h1 + (size_t)b * L0 + ch) = o1;
    *(uint4*)((__hip_bfloat16*)h1 + (size_t)(BATCH + b) * L0 + ch) = o2;
}

// Fused layers 1+2: C = relu(A @ W1b^T + b1); out += C @ W2  (atomic per row)
#define BM 128
#define BN 128
#define BK2 64
__global__ __launch_bounds__(256) void gemm_kernel(const __hip_bfloat16* __restrict__ A,
                                                   const __hip_bfloat16* __restrict__ B,
                                                   const float* __restrict__ bias,
                                                   const float* __restrict__ W2,
                                                   float* __restrict__ out,
                                                   int M, int N, int K) {
    __shared__ __hip_bfloat16 As[BM * BK2];
    __shared__ __hip_bfloat16 Bs[BN * BK2];
    int t = threadIdx.x;
    int bid = blockIdx.x;          // 512 blocks
    int xcd = bid & 7, ii2 = bid >> 3;       // ii2: 0..63
    int by = xcd * 8 + (ii2 >> 3);           // 0..63
    int bx = ii2 & 7;                        // 0..7
    int brow = by * BM, bcol = bx * BN;
    int w = t >> 6, l = t & 63;
    int wr = w >> 1, wc = w & 1;
    f32x4 acc[4][4] = {};
    int row = l & 15, ko = (l >> 4) * 8;
    int swz = (row & 7) * 8;
    for (int k0 = 0; k0 < K; k0 += BK2) {
#pragma unroll
        for (int i = 0; i < 4; ++i) {
            int idx = i * 256 + t;              // 0..1023
            int r = idx >> 3;
            int cb = ((idx & 7) ^ (r & 7)) * 8; // pre-swizzled source col
            __builtin_amdgcn_global_load_lds(
                (const __attribute__((address_space(1))) void*)(A + (size_t)(brow + r) * K + k0 + cb),
                (__attribute__((address_space(3))) void*)(&As[idx * 8]), 16, 0, 0);
            __builtin_amdgcn_global_load_lds(
                (const __attribute__((address_space(1))) void*)(B + (size_t)(bcol + r) * K + k0 + cb),
                (__attribute__((address_space(3))) void*)(&Bs[idx * 8]), 16, 0, 0);
        }
        __syncthreads();
#pragma unroll
        for (int ks = 0; ks < 2; ++ks) {
            int col = (ks * 32 + ko) ^ swz;
            s16x8 af[4], bfr[4];
#pragma unroll
            for (int m = 0; m < 4; ++m)
                af[m] = *(const s16x8*)(&As[(wr * 64 + m * 16 + row) * BK2 + col]);
#pragma unroll
            for (int n = 0; n < 4; ++n)
                bfr[n] = *(const s16x8*)(&Bs[(wc * 64 + n * 16 + row) * BK2 + col]);
#pragma unroll
            for (int m = 0; m < 4; ++m)
#pragma unroll
                for (int n = 0; n < 4; ++n)
                    acc[m][n] = __builtin_amdgcn_mfma_f32_16x16x32_bf16(af[m], bfr[n], acc[m][n], 0, 0, 0);
        }
        __syncthreads();
    }
    int cr = (l >> 4) * 4;
    int cc = l & 15;
#pragma unroll
    for (int m = 0; m < 4; ++m) {
        float s[4] = {0.f, 0.f, 0.f, 0.f};
#pragma unroll
        for (int n = 0; n < 4; ++n) {
            int gcol = bcol + wc * 64 + n * 16 + cc;
            float bv = bias[gcol];
            float wv = W2[gcol];
#pragma unroll
            for (int j = 0; j < 4; ++j) {
                float v = fmaxf(acc[m][n][j] + bv, 0.f);
                s[j] += v * wv;
            }
        }
#pragma unroll
        for (int mask = 1; mask < 16; mask <<= 1) {
#pragma unroll
            for (int j = 0; j < 4; ++j) s[j] += __shfl_xor(s[j], mask);
        }
        if (cc == 0) {
            int grow = brow + wr * 64 + m * 16 + cr;
#pragma unroll
            for (int j = 0; j < 4; ++j) atomicAdd(&out[grow + j], s[j]);
        }
    }
}

extern "C" void kernel_launch(void* const* d_in, const int* in_sizes, int n_in,
                              void* d_out, int out_size, void* d_ws, size_t ws_size,
                              hipStream_t stream) {
    const int* drug_pairs = (const int*)d_in[0];
    const int* cell_lines = (const int*)d_in[1];
    const int* dpi_drug = (const int*)d_in[2];
    const int* dpi_prot = (const int*)d_in[3];
    const float* W0 = (const float*)d_in[4];
    const float* b0 = (const float*)d_in[5];
    const float* W1 = (const float*)d_in[6];
    const float* b1 = (const float*)d_in[7];
    const float* W2 = (const float*)d_in[8];
    const float* b2 = (const float*)d_in[9];
    float* out = (float*)d_out;

    char* ws = (char*)d_ws;
    size_t off = 0;
    auto alloc = [&](size_t bytes) {
        char* p = ws + off;
        off += (bytes + 255) & ~(size_t)255;
        return p;
    };
    __hip_bfloat16* SAb = (__hip_bfloat16*)alloc((size_t)NDRUG * L0 * 2);
    __hip_bfloat16* SBb = (__hip_bfloat16*)alloc((size_t)NDRUG * L0 * 2);
    uint2* SAT = (uint2*)alloc((size_t)2048 * 4096 * 8);
    float* BASE = (float*)alloc((size_t)NCELL * L0 * 4);
    __hip_bfloat16* W1b = (__hip_bfloat16*)alloc((size_t)L1DIM * L0 * 2);
    __hip_bfloat16* h1 = (__hip_bfloat16*)alloc((size_t)2 * BATCH * L0 * 2);
    const int ZREG_N = BMWORDS + 3 * NDRUG;
    int* zreg = (int*)alloc((size_t)ZREG_N * 4);
    unsigned* bitmap = (unsigned*)zreg;
    int* cnt2 = zreg + BMWORDS;
    int* cntTot = zreg + BMWORDS + 2 * NDRUG;
    unsigned short* dlist = (unsigned short*)alloc((size_t)NDRUG * DCAP * 2);
    int* wlen = (int*)alloc(16 * 4);
    int* wbase = (int*)alloc(16 * 4);
    int* pref = (int*)alloc((size_t)512 * 8 * 2 * 4);
    int* tcnt = (int*)alloc((size_t)512 * 2 * 4);
    unsigned short* estream = (unsigned short*)alloc((size_t)64 * (NEDGE + 2 * NDRUG + 2048) * 2);

    zero_all_kernel<<<(ZREG_N + 255) / 256, 256, 0, stream>>>(zreg, ZREG_N);
    scatter_dedup_kernel<<<(NEDGE + 255) / 256, 256, 0, stream>>>(dpi_drug, dpi_prot,
                                                                  bitmap, cnt2, cntTot, dlist);
    stream_meta_kernel<<<1, 512, 0, stream>>>(cnt2, wlen, wbase, pref, tcnt);
    fill_stream_kernel<<<(NDRUG + 1024 + 255) / 256, 256, 0, stream>>>(cnt2, dlist, wbase,
                                                                       wlen, pref, tcnt, estream);
    misc_kernel<<<2208, 256, 0, stream>>>(W0, b0, BASE, W1, W1b, b2, out);
    drug_sum_kernel<<<2048, 512, 0, stream>>>(W0, estream, wbase, wlen, SAT);
    combine_kernel<<<4000, 256, 0, stream>>>(SAT, SAb, SBb);
    build_h_kernel<<<BATCH, 256, 0, stream>>>(drug_pairs, cell_lines, SAb, SBb, BASE, h1);
    gemm_kernel<<<(2 * BATCH / BM) * (L1DIM / BN), 256, 0, stream>>>(h1, W1b, b1, W2, out,
                                                                     2 * BATCH, L1DIM, L0);
}

// Round 22
// 216.307 us; speedup vs baseline: 1.0360x; 1.0360x over previous
//
#include <hip/hip_runtime.h>
#include <hip/hip_bf16.h>
#include <stdint.h>

#define NPROT 19000
#define NDRUG 4000
#define NCELL 16
#define BATCH 4096
#define NEDGE 40000
#define L0 2048
#define L1DIM 1024
#define INDIM 38032
#define HALFDIM 19016
#define DCAP 96      // max deduped proteins per drug (avg 10, tail << 96)
#define BMWORDS ((NDRUG * NPROT + 31) / 32)   // dedup bitmap words
#define PSPLIT 9504  // protein split point (half 0: [0,9504), half 1: [9504,19000))
#define WSLOT 9504   // dummy slot (local index)
#define WSTN2 9512   // uint2 slots: 9504 + 8 pad

typedef float f32x4 __attribute__((ext_vector_type(4)));
typedef short s16x8 __attribute__((ext_vector_type(8)));

__global__ void zero_all_kernel(int* __restrict__ p, int n) {
    int i = blockIdx.x * 256 + threadIdx.x;
    if (i < n) p[i] = 0;
}

// dedup via bitmap; count per (drug, protein-half); append to per-drug list
__global__ void scatter_dedup_kernel(const int* __restrict__ drug, const int* __restrict__ prot,
                                     unsigned* __restrict__ bitmap, int* __restrict__ cnt2,
                                     int* __restrict__ cntTot, unsigned short* __restrict__ dlist) {
    int e = blockIdx.x * 256 + threadIdx.x;
    if (e < NEDGE) {
        int d = drug[e], p = prot[e];
        unsigned idx = (unsigned)d * NPROT + p;
        unsigned bit = 1u << (idx & 31u);
        unsigned old = atomicOr(&bitmap[idx >> 5], bit);
        if (!(old & bit)) {
            int ph = p >= PSPLIT;
            atomicAdd(&cnt2[d * 2 + ph], 1);
            int pos = atomicAdd(&cntTot[d], 1);
            if (pos < DCAP) dlist[d * DCAP + pos] = (unsigned short)p;
        }
    }
}

// per-slot prefix over 8 owned drugs for BOTH protein halves; 16 streams total
__global__ __launch_bounds__(512) void stream_meta_kernel(const int* __restrict__ cnt2,
                                                          int* __restrict__ wlen,
                                                          int* __restrict__ wbase,
                                                          int* __restrict__ pref,
                                                          int* __restrict__ tcnt) {
    __shared__ int wl[16];
    int t = threadIdx.x;
    if (t < 16) wl[t] = 0;
    __syncthreads();
    int c0 = 0, c1 = 0;
#pragma unroll
    for (int k = 0; k < 8; ++k) {
        int d = t + (k << 9);
        pref[((t << 3) + k) * 2 + 0] = c0;
        pref[((t << 3) + k) * 2 + 1] = c1;
        if (d < NDRUG) {
            int n0 = cnt2[d * 2], n1 = cnt2[d * 2 + 1];
            c0 += n0 ? n0 : 1;
            c1 += n1 ? n1 : 1;
        }
    }
    tcnt[t * 2] = c0;
    tcnt[t * 2 + 1] = c1;
    atomicMax(&wl[(t >> 6) * 2], c0);
    atomicMax(&wl[(t >> 6) * 2 + 1], c1);
    __syncthreads();
    if (t == 0) {
        int run = 0;
        for (int s = 0; s < 16; ++s) {
            wlen[s] = wl[s];
            wbase[s] = run;
            run += wl[s] * 64;
        }
    }
}

// drug-parallel fill of the 16 wave-interleaved u16 streams.
// entry = local_p | (last<<15); slot t's i-th entry of stream s at wbase[s]+(t&63)+i*64
__global__ __launch_bounds__(256) void fill_stream_kernel(const int* __restrict__ cnt2,
                                                          const unsigned short* __restrict__ dlist,
                                                          const int* __restrict__ wbase,
                                                          const int* __restrict__ wlen,
                                                          const int* __restrict__ pref,
                                                          const int* __restrict__ tcnt,
                                                          unsigned short* __restrict__ estream) {
    int g = blockIdx.x * 256 + threadIdx.x;
    if (g < NDRUG) {
        int d = g;
        int t = d & 511, k = d >> 9;
        int wv = t >> 6, lane = t & 63;
        int n0 = cnt2[d * 2], n1 = cnt2[d * 2 + 1];
        int base0 = wbase[wv * 2 + 0] + lane;
        int base1 = wbase[wv * 2 + 1] + lane;
        int i0 = pref[((t << 3) + k) * 2 + 0];
        int i1 = pref[((t << 3) + k) * 2 + 1];
        int n = min(n0 + n1, DCAP);
        int j0 = 0, j1 = 0;
        for (int i = 0; i < n; ++i) {
            int p = dlist[d * DCAP + i];
            if (p < PSPLIT) {
                unsigned short e = (unsigned short)(p | ((j0 == n0 - 1) ? 0x8000 : 0));
                estream[base0 + (i0 + j0) * 64] = e;
                ++j0;
            } else {
                unsigned short e = (unsigned short)((p - PSPLIT) | ((j1 == n1 - 1) ? 0x8000 : 0));
                estream[base1 + (i1 + j1) * 64] = e;
                ++j1;
            }
        }
        if (n0 == 0) estream[base0 + i0 * 64] = (unsigned short)(WSLOT | 0x8000);
        if (n1 == 0) estream[base1 + i1 * 64] = (unsigned short)(WSLOT | 0x8000);
    } else if (g < NDRUG + 1024) {
        int idx = g - NDRUG;
        int t = idx >> 1, ph = idx & 1;
        int wv = t >> 6;
        int base = wbase[wv * 2 + ph] + (t & 63);
        int wl = wlen[wv * 2 + ph];
        for (int j = tcnt[t * 2 + ph]; j < wl; ++j)
            estream[base + j * 64] = (unsigned short)WSLOT;
    }
}

// BASE[c][ch] = b0[ch] + W0[ch, 19000+c] + W0[ch, 38016+c]
__global__ void base_kernel(const float* __restrict__ W0, const float* __restrict__ b0,
                            float* __restrict__ BASE) {
    int i = blockIdx.x * 256 + threadIdx.x;
    if (i < NCELL * L0) {
        int c = i >> 11, ch = i & 2047;
        const float* wr = W0 + (size_t)ch * INDIM;
        BASE[(size_t)c * L0 + ch] = b0[ch] + wr[NPROT + c] + wr[HALFDIM + NPROT + c];
    }
}

// RNE f32->bf16 pair pack: low16 = a, high16 = b
__device__ inline unsigned bfpair(float a, float b) {
    unsigned ua = __float_as_uint(a), ub = __float_as_uint(b);
    ua += 0x7fffu + ((ua >> 16) & 1u);
    ub += 0x7fffu + ((ub >> 16) & 1u);
    return (ua >> 16) | (ub & 0xffff0000u);
}
__device__ inline float bflo(unsigned w) { return __uint_as_float(w << 16); }
__device__ inline float bfhi(unsigned w) { return __uint_as_float(w & 0xffff0000u); }

// Split-protein drug sum: block = (protein-half ph, W0-half hb, ch-quad).
// Stage 9504 prot x 4ch packed bf16 = 76KB -> 2 blocks/CU. Walk: per 8-entry
// batch, phase 1 issues all 8 ds_read_b64 (no side effects between reads),
// phase 2 accumulates + flag-stores -> LDS latency paid once per batch, not 8x.
// Emits bf16 partials coalesced: SAT[row][d], row = ph*1024 + hb*512 + quad.
__global__ __launch_bounds__(512) void drug_sum_kernel(const float* __restrict__ W0,
                                                       const unsigned short* __restrict__ estream,
                                                       const int* __restrict__ wbase,
                                                       const int* __restrict__ wlen,
                                                       uint2* __restrict__ SAT) {
    __shared__ uint2 wst[WSTN2];  // 76096 B
    int t = threadIdx.x;
    int bid = blockIdx.x;         // 2048 = ph*1024 + hb*512 + quad
    int ph = bid >> 10;
    int k3 = bid & 1023;
    int hb = k3 >> 9;
    int quad = k3 & 511;
    int ch0 = quad * 4;
    size_t colbase = (size_t)hb * HALFDIM + (size_t)ph * PSPLIT;
    int pc = ph ? (NPROT - PSPLIT) : PSPLIT;   // 9496 or 9504

    // prefetch first estream batch (independent of wst)
    int wv = t >> 6;
    int sid = wv * 2 + ph;
    int base = wbase[sid] + (t & 63);
    int wl = wlen[sid];
    int nfull = wl >> 3, rem = wl & 7;
    unsigned e[8];
    if (nfull > 0) {
#pragma unroll
        for (int k = 0; k < 8; ++k) e[k] = estream[base + k * 64];
        base += 512;
    }

    const float* sA = W0 + (size_t)(ch0 + 0) * INDIM + colbase;
    const float* sB = W0 + (size_t)(ch0 + 1) * INDIM + colbase;
    const float* sC = W0 + (size_t)(ch0 + 2) * INDIM + colbase;
    const float* sD = W0 + (size_t)(ch0 + 3) * INDIM + colbase;
#pragma unroll
    for (int k = 0; k < 4; ++k) {
        int i = t * 4 + k * 2048;   // max 8188 < 9496 : uniform
        float4 a = *(const float4*)(sA + i);
        float4 b = *(const float4*)(sB + i);
        float4 c = *(const float4*)(sC + i);
        float4 d = *(const float4*)(sD + i);
        uint4 q0, q1;
        q0.x = bfpair(a.x, b.x); q0.y = bfpair(c.x, d.x);
        q0.z = bfpair(a.y, b.y); q0.w = bfpair(c.y, d.y);
        q1.x = bfpair(a.z, b.z); q1.y = bfpair(c.z, d.z);
        q1.z = bfpair(a.w, b.w); q1.w = bfpair(c.w, d.w);
        *(uint4*)&wst[i] = q0;
        *(uint4*)&wst[i + 2] = q1;
    }
    {
        int i = t * 4 + 8192;
        if (i < pc) {
            float4 a = *(const float4*)(sA + i);
            float4 b = *(const float4*)(sB + i);
            float4 c = *(const float4*)(sC + i);
            float4 d = *(const float4*)(sD + i);
            uint4 q0, q1;
            q0.x = bfpair(a.x, b.x); q0.y = bfpair(c.x, d.x);
            q0.z = bfpair(a.y, b.y); q0.w = bfpair(c.y, d.y);
            q1.x = bfpair(a.z, b.z); q1.y = bfpair(c.z, d.z);
            q1.z = bfpair(a.w, b.w); q1.w = bfpair(c.w, d.w);
            *(uint4*)&wst[i] = q0;
            *(uint4*)&wst[i + 2] = q1;
        }
    }
    if (t < 8) { wst[WSLOT + t].x = 0u; wst[WSLOT + t].y = 0u; }
    __syncthreads();

    float x0 = 0.f, x1 = 0.f, x2 = 0.f, x3 = 0.f;
    int kk = 0;
    uint2* dstT = SAT + (size_t)bid * 4096;

    // phase-split batch: 8 independent LDS reads, then accumulate+flag
    auto procBatch = [&](const unsigned* ev) {
        uint2 w[8];
#pragma unroll
        for (int k = 0; k < 8; ++k) w[k] = wst[ev[k] & 0x7fffu];
#pragma unroll
        for (int k = 0; k < 8; ++k) {
            x0 += bflo(w[k].x);
            x1 += bfhi(w[k].x);
            x2 += bflo(w[k].y);
            x3 += bfhi(w[k].y);
            if (ev[k] & 0x8000u) {
                uint2 v;
                v.x = bfpair(x0, x1);
                v.y = bfpair(x2, x3);
                dstT[t + (kk << 9)] = v;    // slot == drug id (t + kk*512)
                ++kk; x0 = 0.f; x1 = 0.f; x2 = 0.f; x3 = 0.f;
            }
        }
    };

    if (nfull > 0) {
        for (int it = 1; it < nfull; ++it) {
            unsigned f[8];
#pragma unroll
            for (int k = 0; k < 8; ++k) f[k] = estream[base + k * 64];
            base += 512;
            procBatch(e);
#pragma unroll
            for (int k = 0; k < 8; ++k) e[k] = f[k];
        }
        procBatch(e);
    }
    for (int k = 0; k < rem; ++k) {
        unsigned ev = estream[base + k * 64];
        uint2 w = wst[ev & 0x7fffu];
        x0 += bflo(w.x);
        x1 += bfhi(w.x);
        x2 += bflo(w.y);
        x3 += bfhi(w.y);
        if (ev & 0x8000u) {
            uint2 v;
            v.x = bfpair(x0, x1);
            v.y = bfpair(x2, x3);
            dstT[t + (kk << 9)] = v;
            ++kk; x0 = 0.f; x1 = 0.f; x2 = 0.f; x3 = 0.f;
        }
    }
}

// combine + transpose + pack: SAb/SBb[d][2048] bf16 = (ph0 + ph1) bf16 partials
// grid: 2 hb x 16 quad-tiles x 125 drug-tiles = 4000 blocks of 256
__global__ __launch_bounds__(256) void combine_kernel(const uint2* __restrict__ SAT,
                                                      __hip_bfloat16* __restrict__ SAb,
                                                      __hip_bfloat16* __restrict__ SBb) {
    __shared__ float tile[4][32][33];
    int b = blockIdx.x;
    int hb = b / 2000;
    int rem = b % 2000;
    int q0 = (rem / 125) * 32;
    int d0 = (rem % 125) * 32;
    const uint2* inA = SAT + (size_t)(hb * 512) * 4096;          // ph=0
    const uint2* inB = SAT + (size_t)(1024 + hb * 512) * 4096;   // ph=1
    int tx = threadIdx.x & 31, ty = threadIdx.x >> 5;   // 32 x 8
#pragma unroll
    for (int r = 0; r < 32; r += 8) {
        int q = q0 + r + ty;
        uint2 a = inA[(size_t)q * 4096 + d0 + tx];
        uint2 c = inB[(size_t)q * 4096 + d0 + tx];
        tile[0][r + ty][tx] = bflo(a.x) + bflo(c.x);
        tile[1][r + ty][tx] = bfhi(a.x) + bfhi(c.x);
        tile[2][r + ty][tx] = bflo(a.y) + bflo(c.y);
        tile[3][r + ty][tx] = bfhi(a.y) + bfhi(c.y);
    }
    __syncthreads();
    __hip_bfloat16* out = hb ? SBb : SAb;
#pragma unroll
    for (int r = 0; r < 32; r += 8) {
        int d = d0 + r + ty;
        float x = tile[0][tx][r + ty];
        float y = tile[1][tx][r + ty];
        float z = tile[2][tx][r + ty];
        float w = tile[3][tx][r + ty];
        uint2 v;
        v.x = bfpair(x, y);
        v.y = bfpair(z, w);
        *(uint2*)(out + (size_t)d * L0 + (q0 + tx) * 4) = v;
    }
}

__global__ void cvtw1_kernel(const float* __restrict__ W1, __hip_bfloat16* __restrict__ W1b) {
    int i = blockIdx.x * 256 + threadIdx.x;  // one float4 each
    const int n = L1DIM * L0 / 4;
    if (i < n) {
        float4 v = ((const float4*)W1)[i];
        uint2 q;
        q.x = bfpair(v.x, v.y);
        q.y = bfpair(v.z, v.w);
        ((uint2*)W1b)[i] = q;
    }
}

// h1[b]      = relu(BASE[c] + SA[d1] + SB[d2])  (x1)
// h1[4096+b] = relu(BASE[c] + SA[d2] + SB[d1])  (x2)
__global__ __launch_bounds__(256) void build_h_kernel(const int* __restrict__ dp,
                                                      const int* __restrict__ cl,
                                                      const __hip_bfloat16* __restrict__ SAb,
                                                      const __hip_bfloat16* __restrict__ SBb,
                                                      const float* __restrict__ BASE,
                                                      __hip_bfloat16* __restrict__ h1) {
    int b = blockIdx.x;
    int d1 = dp[2 * b], d2 = dp[2 * b + 1], c = cl[b];
    int ch = threadIdx.x * 8;
    const float* bs = BASE + (size_t)c * L0 + ch;
    uint4 ua1 = *(const uint4*)(SAb + (size_t)d1 * L0 + ch);
    uint4 ua2 = *(const uint4*)(SAb + (size_t)d2 * L0 + ch);
    uint4 us1 = *(const uint4*)(SBb + (size_t)d1 * L0 + ch);
    uint4 us2 = *(const uint4*)(SBb + (size_t)d2 * L0 + ch);
    float4 vb0 = *(const float4*)(bs);
    float4 vb1 = *(const float4*)(bs + 4);
    float bsv[8] = {vb0.x, vb0.y, vb0.z, vb0.w, vb1.x, vb1.y, vb1.z, vb1.w};
    unsigned a1w[4] = {ua1.x, ua1.y, ua1.z, ua1.w};
    unsigned a2w[4] = {ua2.x, ua2.y, ua2.z, ua2.w};
    unsigned s1w[4] = {us1.x, us1.y, us1.z, us1.w};
    unsigned s2w[4] = {us2.x, us2.y, us2.z, us2.w};
    float z1[8], z2[8];
#pragma unroll
    for (int k = 0; k < 4; ++k) {
        z1[2 * k]     = fmaxf(bsv[2 * k]     + bflo(a1w[k]) + bflo(s2w[k]), 0.f);
        z1[2 * k + 1] = fmaxf(bsv[2 * k + 1] + bfhi(a1w[k]) + bfhi(s2w[k]), 0.f);
        z2[2 * k]     = fmaxf(bsv[2 * k]     + bflo(a2w[k]) + bflo(s1w[k]), 0.f);
        z2[2 * k + 1] = fmaxf(bsv[2 * k + 1] + bfhi(a2w[k]) + bfhi(s1w[k]), 0.f);
    }
    uint4 o1, o2;
    o1.x = bfpair(z1[0], z1[1]); o1.y = bfpair(z1[2], z1[3]);
    o1.z = bfpair(z1[4], z1[5]); o1.w = bfpair(z1[6], z1[7]);
    o2.x = bfpair(z2[0], z2[1]); o2.y = bfpair(z2[2], z2[3]);
    o2.z = bfpair(z2[4], z2[5]); o2.w = bfpair(z2[6], z2[7]);
    *(uint4*)((__hip_bfloat16*)h1 + (size_t)b * L0 + ch) = o1;
    *(uint4*)((__hip_bfloat16*)h1 + (size_t)(BATCH + b) * L0 + ch) = o2;
}

// out[i] = b2 (init for fused atomic layer-2)
__global__ void init_out_kernel(float* __restrict__ out, const float* __restrict__ b2, int n) {
    int i = blockIdx.x * 256 + threadIdx.x;
    if (i < n) out[i] = b2[0];
}

// Fused layers 1+2: C = relu(A @ W1b^T + b1); out += C @ W2  (atomic per row)
#define BM 128
#define BN 128
#define BK2 64
__global__ __launch_bounds__(256) void gemm_kernel(const __hip_bfloat16* __restrict__ A,
                                                   const __hip_bfloat16* __restrict__ B,
                                                   const float* __restrict__ bias,
                                                   const float* __restrict__ W2,
                                                   float* __restrict__ out,
                                                   int M, int N, int K) {
    __shared__ __hip_bfloat16 As[BM * BK2];
    __shared__ __hip_bfloat16 Bs[BN * BK2];
    int t = threadIdx.x;
    int bid = blockIdx.x;          // 512 blocks
    int xcd = bid & 7, ii2 = bid >> 3;       // ii2: 0..63
    int by = xcd * 8 + (ii2 >> 3);           // 0..63
    int bx = ii2 & 7;                        // 0..7
    int brow = by * BM, bcol = bx * BN;
    int w = t >> 6, l = t & 63;
    int wr = w >> 1, wc = w & 1;
    f32x4 acc[4][4] = {};
    int row = l & 15, ko = (l >> 4) * 8;
    int swz = (row & 7) * 8;
    for (int k0 = 0; k0 < K; k0 += BK2) {
#pragma unroll
        for (int i = 0; i < 4; ++i) {
            int idx = i * 256 + t;              // 0..1023
            int r = idx >> 3;
            int cb = ((idx & 7) ^ (r & 7)) * 8; // pre-swizzled source col
            __builtin_amdgcn_global_load_lds(
                (const __attribute__((address_space(1))) void*)(A + (size_t)(brow + r) * K + k0 + cb),
                (__attribute__((address_space(3))) void*)(&As[idx * 8]), 16, 0, 0);
            __builtin_amdgcn_global_load_lds(
                (const __attribute__((address_space(1))) void*)(B + (size_t)(bcol + r) * K + k0 + cb),
                (__attribute__((address_space(3))) void*)(&Bs[idx * 8]), 16, 0, 0);
        }
        __syncthreads();
#pragma unroll
        for (int ks = 0; ks < 2; ++ks) {
            int col = (ks * 32 + ko) ^ swz;
            s16x8 af[4], bfr[4];
#pragma unroll
            for (int m = 0; m < 4; ++m)
                af[m] = *(const s16x8*)(&As[(wr * 64 + m * 16 + row) * BK2 + col]);
#pragma unroll
            for (int n = 0; n < 4; ++n)
                bfr[n] = *(const s16x8*)(&Bs[(wc * 64 + n * 16 + row) * BK2 + col]);
#pragma unroll
            for (int m = 0; m < 4; ++m)
#pragma unroll
                for (int n = 0; n < 4; ++n)
                    acc[m][n] = __builtin_amdgcn_mfma_f32_16x16x32_bf16(af[m], bfr[n], acc[m][n], 0, 0, 0);
        }
        __syncthreads();
    }
    int cr = (l >> 4) * 4;
    int cc = l & 15;
#pragma unroll
    for (int m = 0; m < 4; ++m) {
        float s[4] = {0.f, 0.f, 0.f, 0.f};
#pragma unroll
        for (int n = 0; n < 4; ++n) {
            int gcol = bcol + wc * 64 + n * 16 + cc;
            float bv = bias[gcol];
            float wv = W2[gcol];
#pragma unroll
            for (int j = 0; j < 4; ++j) {
                float v = fmaxf(acc[m][n][j] + bv, 0.f);
                s[j] += v * wv;
            }
        }
#pragma unroll
        for (int mask = 1; mask < 16; mask <<= 1) {
#pragma unroll
            for (int j = 0; j < 4; ++j) s[j] += __shfl_xor(s[j], mask);
        }
        if (cc == 0) {
            int grow = brow + wr * 64 + m * 16 + cr;
#pragma unroll
            for (int j = 0; j < 4; ++j) atomicAdd(&out[grow + j], s[j]);
        }
    }
}

extern "C" void kernel_launch(void* const* d_in, const int* in_sizes, int n_in,
                              void* d_out, int out_size, void* d_ws, size_t ws_size,
                              hipStream_t stream) {
    const int* drug_pairs = (const int*)d_in[0];
    const int* cell_lines = (const int*)d_in[1];
    const int* dpi_drug = (const int*)d_in[2];
    const int* dpi_prot = (const int*)d_in[3];
    const float* W0 = (const float*)d_in[4];
    const float* b0 = (const float*)d_in[5];
    const float* W1 = (const float*)d_in[6];
    const float* b1 = (const float*)d_in[7];
    const float* W2 = (const float*)d_in[8];
    const float* b2 = (const float*)d_in[9];
    float* out = (float*)d_out;

    char* ws = (char*)d_ws;
    size_t off = 0;
    auto alloc = [&](size_t bytes) {
        char* p = ws + off;
        off += (bytes + 255) & ~(size_t)255;
        return p;
    };
    __hip_bfloat16* SAb = (__hip_bfloat16*)alloc((size_t)NDRUG * L0 * 2);
    __hip_bfloat16* SBb = (__hip_bfloat16*)alloc((size_t)NDRUG * L0 * 2);
    uint2* SAT = (uint2*)alloc((size_t)2048 * 4096 * 8);
    float* BASE = (float*)alloc((size_t)NCELL * L0 * 4);
    __hip_bfloat16* W1b = (__hip_bfloat16*)alloc((size_t)L1DIM * L0 * 2);
    __hip_bfloat16* h1 = (__hip_bfloat16*)alloc((size_t)2 * BATCH * L0 * 2);
    const int ZREG_N = BMWORDS + 3 * NDRUG;
    int* zreg = (int*)alloc((size_t)ZREG_N * 4);
    unsigned* bitmap = (unsigned*)zreg;
    int* cnt2 = zreg + BMWORDS;
    int* cntTot = zreg + BMWORDS + 2 * NDRUG;
    unsigned short* dlist = (unsigned short*)alloc((size_t)NDRUG * DCAP * 2);
    int* wlen = (int*)alloc(16 * 4);
    int* wbase = (int*)alloc(16 * 4);
    int* pref = (int*)alloc((size_t)512 * 8 * 2 * 4);
    int* tcnt = (int*)alloc((size_t)512 * 2 * 4);
    unsigned short* estream = (unsigned short*)alloc((size_t)64 * (NEDGE + 2 * NDRUG + 2048) * 2);

    zero_all_kernel<<<(ZREG_N + 255) / 256, 256, 0, stream>>>(zreg, ZREG_N);
    scatter_dedup_kernel<<<(NEDGE + 255) / 256, 256, 0, stream>>>(dpi_drug, dpi_prot,
                                                                  bitmap, cnt2, cntTot, dlist);
    stream_meta_kernel<<<1, 512, 0, stream>>>(cnt2, wlen, wbase, pref, tcnt);
    fill_stream_kernel<<<(NDRUG + 1024 + 255) / 256, 256, 0, stream>>>(cnt2, dlist, wbase,
                                                                       wlen, pref, tcnt, estream);
    base_kernel<<<(NCELL * L0 + 255) / 256, 256, 0, stream>>>(W0, b0, BASE);
    drug_sum_kernel<<<2048, 512, 0, stream>>>(W0, estream, wbase, wlen, SAT);
    combine_kernel<<<4000, 256, 0, stream>>>(SAT, SAb, SBb);
    cvtw1_kernel<<<(L1DIM * L0 / 4 + 255) / 256, 256, 0, stream>>>(W1, W1b);
    build_h_kernel<<<BATCH, 256, 0, stream>>>(drug_pairs, cell_lines, SAb, SBb, BASE, h1);
    init_out_kernel<<<(2 * BATCH + 255) / 256, 256, 0, stream>>>(out, b2, 2 * BATCH);
    gemm_kernel<<<(2 * BATCH / BM) * (L1DIM / BN), 256, 0, stream>>>(h1, W1b, b1, W2, out,
                                                                     2 * BATCH, L1DIM, L0);
}